// Round 1
// baseline (1016.223 us; speedup 1.0000x reference)
//
#include <hip/hip_runtime.h>
#include <cstdint>

// Problem constants (B,S,IN,OUT) = (4,512,512,112)
constexpr int B_    = 4;
constexpr int S_    = 512;
constexpr int IN_   = 512;
constexpr int OUT_  = 112;
constexpr int NROW_ = B_ * S_;      // 2048 rows (b,x) or (b,y)
constexpr int NN_   = OUT_ * IN_;   // 57344 = GEMM1 N dim
constexpr int K_    = IN_;          // 512 reduction dim for both GEMMs

typedef __attribute__((ext_vector_type(8))) short          s16x8;  // 8 bf16 = 4 VGPR (MFMA A/B frag)
typedef __attribute__((ext_vector_type(4))) float          f32x4;  // MFMA C/D frag
typedef __attribute__((ext_vector_type(8))) unsigned short u16x8;
typedef __attribute__((ext_vector_type(4))) unsigned short u16x4;

// fp32 -> bf16, round-to-nearest-even
__device__ __forceinline__ unsigned short f2bf(float f) {
  union { float f; unsigned u; } v; v.f = f;
  unsigned u = v.u;
  return (unsigned short)((u + 0x7FFFu + ((u >> 16) & 1u)) >> 16);
}

// async global->LDS, 16B per lane. LDS dest is wave-uniform base + lane*16;
// our per-lane lds ptr is exactly base + lane*16 (rows of 64B, lane>>2 = row, lane&3 = 16B chunk).
__device__ __forceinline__ void gld_lds16(const void* g, void* l) {
  __builtin_amdgcn_global_load_lds(
      (const __attribute__((address_space(1))) unsigned int*)(unsigned long long)g,
      (__attribute__((address_space(3))) unsigned int*)(unsigned int)(unsigned long long)l,
      16, 0, 0);
}

// ---------------- kernel 1: cast input1/input2 to bf16 ----------------
__global__ __launch_bounds__(256) void cast_kernel(
    const float* __restrict__ in1, const float* __restrict__ in2,
    unsigned short* __restrict__ in1b, unsigned short* __restrict__ in2b) {
  int idx = blockIdx.x * 256 + threadIdx.x;          // 262144 float4's
  float4 v1 = ((const float4*)in1)[idx];
  float4 v2 = ((const float4*)in2)[idx];
  ((u16x4*)in1b)[idx] = (u16x4){f2bf(v1.x), f2bf(v1.y), f2bf(v1.z), f2bf(v1.w)};
  ((u16x4*)in2b)[idx] = (u16x4){f2bf(v2.x), f2bf(v2.y), f2bf(v2.z), f2bf(v2.w)};
}

// ---------------- kernel 2: w1 [i][n] fp32 -> w1T [n][i] bf16 ----------------
__global__ __launch_bounds__(256) void transpose_w1(
    const float* __restrict__ w1, unsigned short* __restrict__ w1T) {
  __shared__ unsigned short tile[64][40];
  const int t  = threadIdx.x;
  const int n0 = blockIdx.x * 64;
  const int i0 = blockIdx.y * 32;
#pragma unroll
  for (int p = 0; p < 8; ++p) {
    int il = p * 4 + (t >> 6);
    int nl = t & 63;
    tile[nl][il] = f2bf(w1[(size_t)(i0 + il) * NN_ + n0 + nl]);
  }
  __syncthreads();
  int nl = t >> 2, ch = t & 3;
  u16x8 v = *(const u16x8*)&tile[nl][ch * 8];
  *(u16x8*)&w1T[(size_t)(n0 + nl) * K_ + i0 + ch * 8] = v;
}

// ---------------- kernel 3: termA (incl. bias) / termB ----------------
// NOTE: reference computes termB from input1 (not input2) — replicated.
__global__ __launch_bounds__(128) void term_kernel(
    const float* __restrict__ in1, const float* __restrict__ w2,
    float* __restrict__ termA, float* __restrict__ termB) {
  const int bx = blockIdx.x;          // 0..2047
  const int o  = threadIdx.x;
  if (o >= OUT_) return;
  const float* row = in1 + (size_t)bx * IN_;
  float a = 0.f, c = 0.f;
  for (int i = 0; i < IN_; ++i) {
    float v = row[i];                  // uniform -> scalar load
    a += v * w2[i * OUT_ + o];
    c += v * w2[(IN_ + i) * OUT_ + o];
  }
  termA[bx * OUT_ + o] = a + w2[2 * IN_ * OUT_ + o];   // fold bias into termA
  termB[bx * OUT_ + o] = c;
}

// ---------------- kernel 4: GEMM1  U[bx][n=(o,j)] = in1b[bx][:] . w1T[n][:] ----------------
// M=2048(bx) N=57344 K=512, 128x128x32 tile, 4 waves (2x2), mfma 16x16x32 bf16.
// 2-phase double-buffered LDS (T3-minimum): stage tile t+1, counted vmcnt(4), raw barriers.
// XCD-group swizzle: the 16 m-blocks sharing a w1T n-panel all land on ONE XCD, back-to-back,
// so the panel is fetched from HBM once and served from that XCD's private L2.
__global__ __launch_bounds__(256) void gemm1_kernel(
    const unsigned short* __restrict__ A,   // in1b [2048][512]
    const unsigned short* __restrict__ Bm,  // w1T  [57344][512]
    unsigned short* __restrict__ U) {       // [2048][57344] bf16
  __shared__ unsigned short As[2][128 * 32];
  __shared__ unsigned short Bs[2][128 * 32];
  const int tid = threadIdx.x;
  const int wid = tid >> 6, lane = tid & 63;
  const int wm = wid & 1, wn = wid >> 1;

  // grid = 7168 1-D. xcd = d%8 (HW round-robin); k = d/8 walks per-XCD work.
  const int d   = blockIdx.x;
  const int xcd = d & 7, kk = d >> 3;       // kk 0..895
  const int pan = xcd * 56 + (kk >> 4);     // n-tile 0..447 (56 panels per XCD)
  const int mi  = kk & 15;                  // m-tile 0..15 (16 sharers of a panel)
  const int m0  = mi * 128;
  const int n0  = pan * 128;

  const int rl0 = wid * 16 + (lane >> 2);
  const int rl1 = rl0 + 64;
  const int kcol = lane & 3;

  const unsigned short* aP0 = A + (size_t)(m0 + rl0) * K_ + kcol * 8;
  const unsigned short* aP1 = A + (size_t)(m0 + rl1) * K_ + kcol * 8;
  const unsigned short* bP0 = Bm + (size_t)(n0 + rl0) * K_ + kcol * 8;
  const unsigned short* bP1 = Bm + (size_t)(n0 + rl1) * K_ + kcol * 8;
  const int la0 = rl0 * 32 + kcol * 8;
  const int la1 = rl1 * 32 + kcol * 8;

  const int ln = lane & 15, q = lane >> 4;
  f32x4 acc[4][4];
#pragma unroll
  for (int i = 0; i < 4; ++i)
#pragma unroll
    for (int j = 0; j < 4; ++j) acc[i][j] = (f32x4){0.f, 0.f, 0.f, 0.f};

  auto stage = [&](int bb) {
    gld_lds16(aP0, &As[bb][la0]); gld_lds16(aP1, &As[bb][la1]);
    gld_lds16(bP0, &Bs[bb][la0]); gld_lds16(bP1, &Bs[bb][la1]);
    aP0 += 32; aP1 += 32; bP0 += 32; bP1 += 32;
  };

  constexpr int NT = K_ / 32;   // 16
  stage(0);
  for (int kt = 0; kt < NT; ++kt) {
    const int cur = kt & 1;
    if (kt < NT - 1) {
      stage(cur ^ 1);                                   // 4 new loads in flight
      asm volatile("s_waitcnt vmcnt(4)" ::: "memory");  // my tile-t loads done
    } else {
      asm volatile("s_waitcnt vmcnt(0)" ::: "memory");
    }
    __builtin_amdgcn_s_barrier();                       // everyone's tile-t loads done
    s16x8 af[4], bfr[4];
#pragma unroll
    for (int mf = 0; mf < 4; ++mf)
      af[mf] = *(const s16x8*)&As[cur][(wm * 64 + mf * 16 + ln) * 32 + q * 8];
#pragma unroll
    for (int nf = 0; nf < 4; ++nf)
      bfr[nf] = *(const s16x8*)&Bs[cur][(wn * 64 + nf * 16 + ln) * 32 + q * 8];
    asm volatile("s_waitcnt lgkmcnt(0)" ::: "memory");  // reads landed in regs
    __builtin_amdgcn_s_barrier();                       // safe to overwrite buf[cur] next iter
#pragma unroll
    for (int mf = 0; mf < 4; ++mf)
#pragma unroll
      for (int nf = 0; nf < 4; ++nf)
        acc[mf][nf] = __builtin_amdgcn_mfma_f32_16x16x32_bf16(af[mf], bfr[nf], acc[mf][nf], 0, 0, 0);
  }
  // D layout: row m = q*4 + reg, col n = lane&15 (m89/m91-verified)
#pragma unroll
  for (int mf = 0; mf < 4; ++mf) {
    const int mrow = m0 + wm * 64 + mf * 16 + q * 4;
#pragma unroll
    for (int nf = 0; nf < 4; ++nf) {
      const int ncol = n0 + wn * 64 + nf * 16 + ln;
#pragma unroll
      for (int r = 0; r < 4; ++r)
        U[(size_t)(mrow + r) * NN_ + ncol] = f2bf(acc[mf][nf][r]);
    }
  }
}

// ---------------- kernel 5: GEMM2 + epilogue ----------------
// per b: out[y][(x,o)] = in2b[b][y][:] . U[b*512+x][o*512 .. +511]  + termA[b][x][o] + termB[b][y][o]
// Same 2-phase dbuf structure. XCD-group swizzle: the 4 m-blocks sharing a U n-panel -> one XCD.
__global__ __launch_bounds__(256) void gemm2_kernel(
    const unsigned short* __restrict__ A,   // in2b [4][512][512]
    const unsigned short* __restrict__ U,   // [4*512][112*512]
    const float* __restrict__ termA,        // [4][57344]  (bias folded in)
    const float* __restrict__ termB,        // [4][512][112]
    float* __restrict__ out) {              // [4][512][512][112]
  __shared__ unsigned short As[2][128 * 32];
  __shared__ unsigned short Bs[2][128 * 32];
  const int tid = threadIdx.x;
  const int wid = tid >> 6, lane = tid & 63;
  const int wm = wid & 1, wn = wid >> 1;

  // grid = 7168 1-D. panels = (b,n) pairs: 4*448 = 1792; 224 per XCD; 4 m-sharers each.
  const int d   = blockIdx.x;
  const int xcd = d & 7, kk = d >> 3;       // kk 0..895
  const int pan = xcd * 224 + (kk >> 2);    // 0..1791
  const int mi  = kk & 3;                   // m-tile 0..3
  const int b   = pan / 448;
  const int ni  = pan - b * 448;
  const int m0  = mi * 128;                 // y
  const int n0  = ni * 128;                 // (x,o)

  const int rl0 = wid * 16 + (lane >> 2);
  const int rl1 = rl0 + 64;
  const int kcol = lane & 3;

  const unsigned short* aP0 = A + (size_t)(b * S_ + m0 + rl0) * K_ + kcol * 8;
  const unsigned short* aP1 = A + (size_t)(b * S_ + m0 + rl1) * K_ + kcol * 8;
  const int r2 = n0 + rl0, x0r = r2 / OUT_, o0r = r2 - x0r * OUT_;
  const int r3 = n0 + rl1, x1r = r3 / OUT_, o1r = r3 - x1r * OUT_;
  const unsigned short* bP0 = U + (size_t)(b * S_ + x0r) * NN_ + o0r * K_ + kcol * 8;
  const unsigned short* bP1 = U + (size_t)(b * S_ + x1r) * NN_ + o1r * K_ + kcol * 8;
  const int la0 = rl0 * 32 + kcol * 8;
  const int la1 = rl1 * 32 + kcol * 8;

  const int ln = lane & 15, q = lane >> 4;
  f32x4 acc[4][4];
#pragma unroll
  for (int i = 0; i < 4; ++i)
#pragma unroll
    for (int j = 0; j < 4; ++j) acc[i][j] = (f32x4){0.f, 0.f, 0.f, 0.f};

  auto stage = [&](int bb) {
    gld_lds16(aP0, &As[bb][la0]); gld_lds16(aP1, &As[bb][la1]);
    gld_lds16(bP0, &Bs[bb][la0]); gld_lds16(bP1, &Bs[bb][la1]);
    aP0 += 32; aP1 += 32; bP0 += 32; bP1 += 32;
  };

  constexpr int NT = K_ / 32;   // 16
  stage(0);
  for (int kt = 0; kt < NT; ++kt) {
    const int cur = kt & 1;
    if (kt < NT - 1) {
      stage(cur ^ 1);
      asm volatile("s_waitcnt vmcnt(4)" ::: "memory");
    } else {
      asm volatile("s_waitcnt vmcnt(0)" ::: "memory");
    }
    __builtin_amdgcn_s_barrier();
    s16x8 af[4], bfr[4];
#pragma unroll
    for (int mf = 0; mf < 4; ++mf)
      af[mf] = *(const s16x8*)&As[cur][(wm * 64 + mf * 16 + ln) * 32 + q * 8];
#pragma unroll
    for (int nf = 0; nf < 4; ++nf)
      bfr[nf] = *(const s16x8*)&Bs[cur][(wn * 64 + nf * 16 + ln) * 32 + q * 8];
    asm volatile("s_waitcnt lgkmcnt(0)" ::: "memory");
    __builtin_amdgcn_s_barrier();
#pragma unroll
    for (int mf = 0; mf < 4; ++mf)
#pragma unroll
      for (int nf = 0; nf < 4; ++nf)
        acc[mf][nf] = __builtin_amdgcn_mfma_f32_16x16x32_bf16(af[mf], bfr[nf], acc[mf][nf], 0, 0, 0);
  }

#pragma unroll
  for (int nf = 0; nf < 4; ++nf) {
    const int n = n0 + wn * 64 + nf * 16 + ln;
    const int x = n / OUT_, o = n - x * OUT_;
    const float tA = termA[b * NN_ + n];
    const float* tB = termB + b * NN_ + o;
    float* op = out + ((size_t)(b * S_ + x) * S_) * OUT_ + o;
#pragma unroll
    for (int mf = 0; mf < 4; ++mf) {
      const int y0 = m0 + wm * 64 + mf * 16 + q * 4;
#pragma unroll
      for (int r = 0; r < 4; ++r) {
        const int y = y0 + r;
        op[(size_t)y * OUT_] = acc[mf][nf][r] + tA + tB[y * OUT_];
      }
    }
  }
}

extern "C" void kernel_launch(void* const* d_in, const int* in_sizes, int n_in,
                              void* d_out, int out_size, void* d_ws, size_t ws_size,
                              hipStream_t stream) {
  const float* in1 = (const float*)d_in[0];
  const float* in2 = (const float*)d_in[1];
  const float* w1  = (const float*)d_in[2];
  const float* w2  = (const float*)d_in[3];
  float* out = (float*)d_out;

  char* ws = (char*)d_ws;
  size_t off = 0;
  unsigned short* w1T  = (unsigned short*)(ws + off); off += (size_t)NN_ * K_ * 2;     //  58.7 MB
  unsigned short* U    = (unsigned short*)(ws + off); off += (size_t)NROW_ * NN_ * 2;  // 234.9 MB
  unsigned short* in1b = (unsigned short*)(ws + off); off += (size_t)NROW_ * IN_ * 2;  //   2.1 MB
  unsigned short* in2b = (unsigned short*)(ws + off); off += (size_t)NROW_ * IN_ * 2;  //   2.1 MB
  float* termA = (float*)(ws + off); off += (size_t)NROW_ * OUT_ * 4;                  //   0.9 MB
  float* termB = (float*)(ws + off); off += (size_t)NROW_ * OUT_ * 4;                  //   0.9 MB
  if (ws_size < off) return;

  cast_kernel<<<(NROW_ * IN_ / 4) / 256, 256, 0, stream>>>(in1, in2, in1b, in2b);
  transpose_w1<<<dim3(NN_ / 64, K_ / 32), 256, 0, stream>>>(w1, w1T);
  term_kernel<<<NROW_, 128, 0, stream>>>(in1, w2, termA, termB);
  gemm1_kernel<<<7168, 256, 0, stream>>>(in1b, w1T, U);
  gemm2_kernel<<<7168, 256, 0, stream>>>(in2b, U, termA, termB, out);
}

// Round 2
// 998.703 us; speedup vs baseline: 1.0175x; 1.0175x over previous
//
#include <hip/hip_runtime.h>
#include <cstdint>

// Problem constants (B,S,IN,OUT) = (4,512,512,112)
constexpr int B_    = 4;
constexpr int S_    = 512;
constexpr int IN_   = 512;
constexpr int OUT_  = 112;
constexpr int NROW_ = B_ * S_;      // 2048 rows (b,x) or (b,y)
constexpr int NN_   = OUT_ * IN_;   // 57344 = GEMM1 N dim
constexpr int K_    = IN_;          // 512 reduction dim for both GEMMs

typedef __attribute__((ext_vector_type(8))) short          s16x8;  // 8 bf16 = 4 VGPR (MFMA A/B frag)
typedef __attribute__((ext_vector_type(4))) float          f32x4;  // MFMA C/D frag
typedef __attribute__((ext_vector_type(8))) unsigned short u16x8;
typedef __attribute__((ext_vector_type(4))) unsigned short u16x4;

// fp32 -> bf16, round-to-nearest-even
__device__ __forceinline__ unsigned short f2bf(float f) {
  union { float f; unsigned u; } v; v.f = f;
  unsigned u = v.u;
  return (unsigned short)((u + 0x7FFFu + ((u >> 16) & 1u)) >> 16);
}

// async global->LDS, 16B per lane. LDS dest is wave-uniform base + lane*16 (linear);
// swizzled layouts are achieved by permuting the per-lane GLOBAL source address (rule 21).
__device__ __forceinline__ void gld_lds16(const void* g, void* l) {
  __builtin_amdgcn_global_load_lds(
      (const __attribute__((address_space(1))) unsigned int*)(unsigned long long)g,
      (__attribute__((address_space(3))) unsigned int*)(unsigned int)(unsigned long long)l,
      16, 0, 0);
}

// ---------------- kernel 1: cast input1/input2 to bf16 ----------------
__global__ __launch_bounds__(256) void cast_kernel(
    const float* __restrict__ in1, const float* __restrict__ in2,
    unsigned short* __restrict__ in1b, unsigned short* __restrict__ in2b) {
  int idx = blockIdx.x * 256 + threadIdx.x;          // 262144 float4's
  float4 v1 = ((const float4*)in1)[idx];
  float4 v2 = ((const float4*)in2)[idx];
  ((u16x4*)in1b)[idx] = (u16x4){f2bf(v1.x), f2bf(v1.y), f2bf(v1.z), f2bf(v1.w)};
  ((u16x4*)in2b)[idx] = (u16x4){f2bf(v2.x), f2bf(v2.y), f2bf(v2.z), f2bf(v2.w)};
}

// ---------------- kernel 2: w1 [i][n] fp32 -> w1T [n][i] bf16 ----------------
__global__ __launch_bounds__(256) void transpose_w1(
    const float* __restrict__ w1, unsigned short* __restrict__ w1T) {
  __shared__ unsigned short tile[64][40];
  const int t  = threadIdx.x;
  const int n0 = blockIdx.x * 64;
  const int i0 = blockIdx.y * 32;
#pragma unroll
  for (int p = 0; p < 8; ++p) {
    int il = p * 4 + (t >> 6);
    int nl = t & 63;
    tile[nl][il] = f2bf(w1[(size_t)(i0 + il) * NN_ + n0 + nl]);
  }
  __syncthreads();
  int nl = t >> 2, ch = t & 3;
  u16x8 v = *(const u16x8*)&tile[nl][ch * 8];
  *(u16x8*)&w1T[(size_t)(n0 + nl) * K_ + i0 + ch * 8] = v;
}

// ---------------- kernel 3: termA (incl. bias) / termB ----------------
// NOTE: reference computes termB from input1 (not input2) — replicated.
__global__ __launch_bounds__(128) void term_kernel(
    const float* __restrict__ in1, const float* __restrict__ w2,
    float* __restrict__ termA, float* __restrict__ termB) {
  const int bx = blockIdx.x;          // 0..2047
  const int o  = threadIdx.x;
  if (o >= OUT_) return;
  const float* row = in1 + (size_t)bx * IN_;
  float a = 0.f, c = 0.f;
  for (int i = 0; i < IN_; ++i) {
    float v = row[i];                  // uniform -> scalar load
    a += v * w2[i * OUT_ + o];
    c += v * w2[(IN_ + i) * OUT_ + o];
  }
  termA[bx * OUT_ + o] = a + w2[2 * IN_ * OUT_ + o];   // fold bias into termA
  termB[bx * OUT_ + o] = c;
}

// =====================================================================
// 256x256 tile, BK=64, 8 waves (2M x 4N), 512 threads. LDS 128KB, 1 blk/CU.
// LDS layout: [row][64 cols bf16] = 128B rows, with XOR swizzle chunk ^= (row&7)
// (chunk = 16B unit). Staging keeps LDS dest LINEAR (global_load_lds requirement)
// and applies the INVERSE permutation to the global source chunk; frag reads
// apply the same permutation. All swizzle terms fold into per-thread constants.
// A full-wave ds_read_b128 then touches all 32 banks at depth 8 (optimal).
// =====================================================================

// ---------------- kernel 4: GEMM1  U[bx][n=(o,j)] = in1b[bx][:] . w1T[n][:] ----------------
// M=2048 N=57344 K=512. Grid 1792: XCD-group swizzle, 8 m-sharers per n-panel.
__global__ __launch_bounds__(512, 2) void gemm1_kernel(
    const unsigned short* __restrict__ A,   // in1b [2048][512]
    const unsigned short* __restrict__ Bm,  // w1T  [57344][512]
    unsigned short* __restrict__ U) {       // [2048][57344] bf16
  __shared__ unsigned short As[2][256 * 64];
  __shared__ unsigned short Bs[2][256 * 64];
  const int t = threadIdx.x;
  const int wid = t >> 6, lane = t & 63;
  const int wm = wid >> 2, wn = wid & 3;         // 2 x 4 wave grid

  // XCD-group: 224 n-panels, 28 per XCD; 8 m-tiles share each panel back-to-back.
  const int d   = blockIdx.x;
  const int xcd = d & 7, kk = d >> 3;            // kk 0..223
  const int pan = xcd * 28 + (kk >> 3);          // n-tile 0..223
  const int mi  = kk & 7;                        // m-tile 0..7
  const int m0  = mi * 256;
  const int n0  = pan * 256;

  // staging: load l covers rows l*64 + (t>>3); phys chunk t&7; src chunk = phys ^ (row&7)
  const int srow = t >> 3;
  const int scx  = (t & 7) ^ (srow & 7);
  const unsigned short* aP[4];
  const unsigned short* bP[4];
#pragma unroll
  for (int l = 0; l < 4; ++l) {
    aP[l] = A  + (size_t)(m0 + l * 64 + srow) * K_ + scx * 8;
    bP[l] = Bm + (size_t)(n0 + l * 64 + srow) * K_ + scx * 8;
  }

  auto stage = [&](int bb) {
#pragma unroll
    for (int l = 0; l < 4; ++l) gld_lds16(aP[l], &As[bb][l * 4096 + t * 8]);
#pragma unroll
    for (int l = 0; l < 4; ++l) gld_lds16(bP[l], &Bs[bb][l * 4096 + t * 8]);
#pragma unroll
    for (int l = 0; l < 4; ++l) { aP[l] += 64; bP[l] += 64; }
  };

  const int ln = lane & 15, q = lane >> 4;
  f32x4 acc[8][4];
#pragma unroll
  for (int i = 0; i < 8; ++i)
#pragma unroll
    for (int j = 0; j < 4; ++j) acc[i][j] = (f32x4){0.f, 0.f, 0.f, 0.f};

  constexpr int NT = K_ / 64;   // 8
  stage(0);
#pragma unroll
  for (int kt = 0; kt < NT; ++kt) {
    const int cur = kt & 1;
    if (kt < NT - 1) {
      stage(cur ^ 1);                                   // 8 new loads in flight
      asm volatile("s_waitcnt vmcnt(8)" ::: "memory");  // my tile-kt loads done
    } else {
      asm volatile("s_waitcnt vmcnt(0)" ::: "memory");
    }
    __builtin_amdgcn_s_barrier();                       // all waves' tile-kt loads done
#pragma unroll
    for (int ks = 0; ks < 2; ++ks) {
      s16x8 af[8], bfr[4];
#pragma unroll
      for (int mf = 0; mf < 8; ++mf) {
        const int row = wm * 128 + mf * 16 + ln;
        const int pc  = ((ks * 4 + q) ^ (ln & 7));      // swizzled 16B chunk
        af[mf] = *(const s16x8*)&As[cur][row * 64 + pc * 8];
      }
#pragma unroll
      for (int nf = 0; nf < 4; ++nf) {
        const int row = wn * 64 + nf * 16 + ln;
        const int pc  = ((ks * 4 + q) ^ (ln & 7));
        bfr[nf] = *(const s16x8*)&Bs[cur][row * 64 + pc * 8];
      }
#pragma unroll
      for (int mf = 0; mf < 8; ++mf)
#pragma unroll
        for (int nf = 0; nf < 4; ++nf)
          acc[mf][nf] = __builtin_amdgcn_mfma_f32_16x16x32_bf16(af[mf], bfr[nf], acc[mf][nf], 0, 0, 0);
    }
    asm volatile("s_waitcnt lgkmcnt(0)" ::: "memory");  // frag reads landed
    __builtin_amdgcn_s_barrier();                       // safe to overwrite buf[cur]
  }

  // D layout: row m = q*4 + reg, col n = lane&15 (verified convention)
#pragma unroll
  for (int mf = 0; mf < 8; ++mf) {
    const int mrow = m0 + wm * 128 + mf * 16 + q * 4;
#pragma unroll
    for (int nf = 0; nf < 4; ++nf) {
      const int ncol = n0 + wn * 64 + nf * 16 + ln;
#pragma unroll
      for (int r = 0; r < 4; ++r)
        U[(size_t)(mrow + r) * NN_ + ncol] = f2bf(acc[mf][nf][r]);
    }
  }
}

// ---------------- kernel 5: GEMM2 + epilogue ----------------
// per b: out[y][(x,o)] = in2b[b][y][:] . U[b*512+x][o*512 .. +511] + termA[b][x][o] + termB[b][y][o]
// M=512 per b (2 m-tiles), 224 n-tiles, 4 b -> 1792 blocks. 2 m-sharers per (b,n) panel.
__global__ __launch_bounds__(512, 2) void gemm2_kernel(
    const unsigned short* __restrict__ A,   // in2b [4][512][512]
    const unsigned short* __restrict__ U,   // [4*512][112*512]
    const float* __restrict__ termA,        // [4][57344]  (bias folded in)
    const float* __restrict__ termB,        // [4][512][112]
    float* __restrict__ out) {              // [4][512][512][112]
  __shared__ unsigned short As[2][256 * 64];
  __shared__ unsigned short Bs[2][256 * 64];
  const int t = threadIdx.x;
  const int wid = t >> 6, lane = t & 63;
  const int wm = wid >> 2, wn = wid & 3;

  // XCD-group: 896 (b,n) panels, 112 per XCD; 2 m-sharers each.
  const int d   = blockIdx.x;
  const int xcd = d & 7, kk = d >> 3;            // kk 0..223
  const int pan = xcd * 112 + (kk >> 1);         // 0..895
  const int mi  = kk & 1;                        // m-tile 0..1
  const int b   = pan / 224;
  const int ni  = pan - b * 224;
  const int m0  = mi * 256;                      // y
  const int n0  = ni * 256;                      // (x,o)

  const int srow = t >> 3;
  const int scx  = (t & 7) ^ (srow & 7);
  const unsigned short* aP[4];
  const unsigned short* bP[4];
#pragma unroll
  for (int l = 0; l < 4; ++l) {
    aP[l] = A + (size_t)(b * S_ + m0 + l * 64 + srow) * K_ + scx * 8;
    const int n = n0 + l * 64 + srow;
    const int x = n / OUT_, o = n - x * OUT_;
    bP[l] = U + (size_t)(b * S_ + x) * NN_ + o * K_ + scx * 8;
  }

  auto stage = [&](int bb) {
#pragma unroll
    for (int l = 0; l < 4; ++l) gld_lds16(aP[l], &As[bb][l * 4096 + t * 8]);
#pragma unroll
    for (int l = 0; l < 4; ++l) gld_lds16(bP[l], &Bs[bb][l * 4096 + t * 8]);
#pragma unroll
    for (int l = 0; l < 4; ++l) { aP[l] += 64; bP[l] += 64; }
  };

  const int ln = lane & 15, q = lane >> 4;
  f32x4 acc[8][4];
#pragma unroll
  for (int i = 0; i < 8; ++i)
#pragma unroll
    for (int j = 0; j < 4; ++j) acc[i][j] = (f32x4){0.f, 0.f, 0.f, 0.f};

  constexpr int NT = K_ / 64;   // 8
  stage(0);
#pragma unroll
  for (int kt = 0; kt < NT; ++kt) {
    const int cur = kt & 1;
    if (kt < NT - 1) {
      stage(cur ^ 1);
      asm volatile("s_waitcnt vmcnt(8)" ::: "memory");
    } else {
      asm volatile("s_waitcnt vmcnt(0)" ::: "memory");
    }
    __builtin_amdgcn_s_barrier();
#pragma unroll
    for (int ks = 0; ks < 2; ++ks) {
      s16x8 af[8], bfr[4];
#pragma unroll
      for (int mf = 0; mf < 8; ++mf) {
        const int row = wm * 128 + mf * 16 + ln;
        const int pc  = ((ks * 4 + q) ^ (ln & 7));
        af[mf] = *(const s16x8*)&As[cur][row * 64 + pc * 8];
      }
#pragma unroll
      for (int nf = 0; nf < 4; ++nf) {
        const int row = wn * 64 + nf * 16 + ln;
        const int pc  = ((ks * 4 + q) ^ (ln & 7));
        bfr[nf] = *(const s16x8*)&Bs[cur][row * 64 + pc * 8];
      }
#pragma unroll
      for (int mf = 0; mf < 8; ++mf)
#pragma unroll
        for (int nf = 0; nf < 4; ++nf)
          acc[mf][nf] = __builtin_amdgcn_mfma_f32_16x16x32_bf16(af[mf], bfr[nf], acc[mf][nf], 0, 0, 0);
    }
    asm volatile("s_waitcnt lgkmcnt(0)" ::: "memory");
    __builtin_amdgcn_s_barrier();
  }

#pragma unroll
  for (int nf = 0; nf < 4; ++nf) {
    const int n = n0 + wn * 64 + nf * 16 + ln;
    const int x = n / OUT_, o = n - x * OUT_;
    const float tA = termA[b * NN_ + n];
    const float* tB = termB + b * NN_ + o;
    float* op = out + ((size_t)(b * S_ + x) * S_) * OUT_ + o;
#pragma unroll
    for (int mf = 0; mf < 8; ++mf) {
      const int y0 = m0 + wm * 128 + mf * 16 + q * 4;
#pragma unroll
      for (int r = 0; r < 4; ++r) {
        const int y = y0 + r;
        op[(size_t)y * OUT_] = acc[mf][nf][r] + tA + tB[y * OUT_];
      }
    }
  }
}

extern "C" void kernel_launch(void* const* d_in, const int* in_sizes, int n_in,
                              void* d_out, int out_size, void* d_ws, size_t ws_size,
                              hipStream_t stream) {
  const float* in1 = (const float*)d_in[0];
  const float* in2 = (const float*)d_in[1];
  const float* w1  = (const float*)d_in[2];
  const float* w2  = (const float*)d_in[3];
  float* out = (float*)d_out;

  char* ws = (char*)d_ws;
  size_t off = 0;
  unsigned short* w1T  = (unsigned short*)(ws + off); off += (size_t)NN_ * K_ * 2;     //  58.7 MB
  unsigned short* U    = (unsigned short*)(ws + off); off += (size_t)NROW_ * NN_ * 2;  // 234.9 MB
  unsigned short* in1b = (unsigned short*)(ws + off); off += (size_t)NROW_ * IN_ * 2;  //   2.1 MB
  unsigned short* in2b = (unsigned short*)(ws + off); off += (size_t)NROW_ * IN_ * 2;  //   2.1 MB
  float* termA = (float*)(ws + off); off += (size_t)NROW_ * OUT_ * 4;                  //   0.9 MB
  float* termB = (float*)(ws + off); off += (size_t)NROW_ * OUT_ * 4;                  //   0.9 MB
  if (ws_size < off) return;

  cast_kernel<<<(NROW_ * IN_ / 4) / 256, 256, 0, stream>>>(in1, in2, in1b, in2b);
  transpose_w1<<<dim3(NN_ / 64, K_ / 32), 256, 0, stream>>>(w1, w1T);
  term_kernel<<<NROW_, 128, 0, stream>>>(in1, w2, termA, termB);
  gemm1_kernel<<<1792, 512, 0, stream>>>(in1b, w1T, U);
  gemm2_kernel<<<1792, 512, 0, stream>>>(in2b, U, termA, termB, out);
}